// Round 4
// baseline (60.390 us; speedup 1.0000x reference)
//
#include <hip/hip_runtime.h>
#include <hip/hip_bf16.h>

#define E_TOT 50000
#define NF    64
#define B_TOT 64
#define ECH   4              // e's per wave
#define BLOCK 256            // 4 waves per block
#define EPB   16             // e's per block = 4 waves * ECH
// grid = E_TOT / EPB = 3125 exactly

// out[b,e] = sum_f exp(-(HL[b,f] - NL[e,f] - c[f])^2 / var[f]) * W[b,f]
// Folding: q[f]=sqrt(log2e/var[f]); A[b,f]=(HL-c)*q; nlq=NL*q; phi=exp2(-(A-nlq)^2)
//
// R4: batch index b lives on the LANE (B=64=wave size).
//  - AT[f][b], WT[f][b] (transposed, from prep kernel): per-lane coalesced
//    global loads, 32KB total -> L1-resident, loaded once per f.
//  - nlq[e,f] is wave-uniform: staged per-wave in LDS, one broadcast
//    ds_read_b128 per f yields n for the wave's 4 e's.
//  - No __syncthreads anywhere (wave-private LDS regions).
//  - NL read exactly once. Output: 16B-per-lane scatter, merged in L2.

__global__ void prep_kernel(const float* __restrict__ NL,
                            const float* __restrict__ c,
                            const float* __restrict__ varr,
                            const float* __restrict__ NFW,
                            const int*   __restrict__ head_ids,
                            const int*   __restrict__ rel_ids,
                            float*       __restrict__ ws)
{
    const int idx = blockIdx.x * 256 + threadIdx.x;  // 0..4095 = f*64+b
    const int f = idx >> 6;
    const int b = idx & 63;
    const float q = sqrtf(1.4426950408889634f / varr[f]);
    const int h = head_ids[b];
    const int r = rel_ids[b];
    ws[idx]               = (NL[(size_t)h * NF + f] - c[f]) * q;  // AT[f][b]
    ws[NF * B_TOT + idx]  = NFW[(size_t)r * NF + f];              // WT[f][b]
}

__global__ __launch_bounds__(BLOCK, 8)
void kbln_kernel(const float* __restrict__ NL,    // [E, F]
                 const float* __restrict__ varr,  // [F]
                 const float* __restrict__ AW,    // ws: AT[F][B] ++ WT[F][B]
                 float*       __restrict__ out)   // [B, E]
{
    __shared__ float nlq[4][NF][ECH];   // 4KB: per-wave private regions

    const int tid   = threadIdx.x;
    const int w     = tid >> 6;
    const int lane  = tid & 63;
    const int ebase = blockIdx.x * EPB + w * ECH;

    // q for this lane's feature (staging multiplies NL[e][f=lane] by q[lane])
    const float q = sqrtf(1.4426950408889634f / varr[lane]);

    // Stage this wave's 4 NL rows, pre-scaled: nlq[w][f][j] = NL[e_j][f]*q[f]
    float4 st;
    st.x = NL[(size_t)(ebase + 0) * NF + lane] * q;
    st.y = NL[(size_t)(ebase + 1) * NF + lane] * q;
    st.z = NL[(size_t)(ebase + 2) * NF + lane] * q;
    st.w = NL[(size_t)(ebase + 3) * NF + lane] * q;
    *reinterpret_cast<float4*>(&nlq[w][lane][0]) = st;
    // wave-synchronous: compiler inserts the lgkmcnt wait before the reads

    const float* AT = AW;
    const float* WT = AW + NF * B_TOT;

    float acc0 = 0.f, acc1 = 0.f, acc2 = 0.f, acc3 = 0.f;

#pragma unroll 8
    for (int f = 0; f < NF; ++f) {
        const float a   = AT[f * B_TOT + lane];  // coalesced, L1-hot
        const float wgt = WT[f * B_TOT + lane];
        const float4 n  = *reinterpret_cast<const float4*>(&nlq[w][f][0]);
        float t;
        t = a - n.x; acc0 = fmaf(__builtin_amdgcn_exp2f(-(t * t)), wgt, acc0);
        t = a - n.y; acc1 = fmaf(__builtin_amdgcn_exp2f(-(t * t)), wgt, acc1);
        t = a - n.z; acc2 = fmaf(__builtin_amdgcn_exp2f(-(t * t)), wgt, acc2);
        t = a - n.w; acc3 = fmaf(__builtin_amdgcn_exp2f(-(t * t)), wgt, acc3);
    }

    // lane b writes out[b][ebase..ebase+3]; row start is 16B-aligned
    float4 o = make_float4(acc0, acc1, acc2, acc3);
    *reinterpret_cast<float4*>(&out[(size_t)lane * E_TOT + ebase]) = o;
}

extern "C" void kernel_launch(void* const* d_in, const int* in_sizes, int n_in,
                              void* d_out, int out_size, void* d_ws, size_t ws_size,
                              hipStream_t stream)
{
    const float* NL       = (const float*)d_in[0];
    const float* c        = (const float*)d_in[1];
    const float* varr     = (const float*)d_in[2];
    const float* NFW      = (const float*)d_in[3];
    const int*   head_ids = (const int*)d_in[4];
    const int*   rel_ids  = (const int*)d_in[5];
    float*       ws       = (float*)d_ws;
    float*       out      = (float*)d_out;

    prep_kernel<<<dim3(16), dim3(256), 0, stream>>>(NL, c, varr, NFW,
                                                    head_ids, rel_ids, ws);

    kbln_kernel<<<dim3(E_TOT / EPB), dim3(BLOCK), 0, stream>>>(NL, varr, ws, out);
}

// Round 5
// 53.918 us; speedup vs baseline: 1.1200x; 1.1200x over previous
//
#include <hip/hip_runtime.h>
#include <hip/hip_bf16.h>

#define E_TOT 50000
#define NF    64
#define B_TOT 64
#define B_TILE 4
#define BLOCK 256

// out[b,e] = sum_f exp(-(HL[b,f] - NL[e,f] - c[f])^2 / var[f]) * W[b,f]
// Folding: q[f] = sqrt(log2e/var[f]); A[b,f] = (HL[b,f]-c[f])*q[f];
//          nlq = NL[e,f]*q[f]; phi = exp2(-(A-nlq)^2).
// R5: R2 structure (thread=e, LDS-broadcast A/W, i-outer bi-inner acc chains)
// with B_TILE 8->4 and grid.y 8->16: 3136 blocks = 12.25 blocks/CU so the
// 32-wave/CU cap saturates. Trans pipe (v_exp_f32, ~8cyc/wave) is the target
// bottleneck at ~10.5us; everything else rides parallel pipes.
__global__ __launch_bounds__(BLOCK, 8)
void kbln_kernel(const float* __restrict__ NL,       // [E, F]
                 const float* __restrict__ c,        // [F]
                 const float* __restrict__ varr,     // [F]
                 const float* __restrict__ NFW,      // [R, F]
                 const int*   __restrict__ head_ids, // [B]
                 const int*   __restrict__ rel_ids,  // [B]
                 float*       __restrict__ out)      // [B, E]
{
    __shared__ float sQ[NF];
    __shared__ float4 sA[B_TILE][NF / 4];
    __shared__ float4 sW[B_TILE][NF / 4];

    const int tid = threadIdx.x;
    const int b0  = blockIdx.y * B_TILE;
    const int e   = blockIdx.x * BLOCK + tid;

    if (tid < NF) {
        sQ[tid] = sqrtf(1.4426950408889634f / varr[tid]);
    }
    __syncthreads();

    // Stage folded head literals A and weights W for this block's 4 b's.
    if (tid < B_TILE * NF) {
        const int bi = tid >> 6;
        const int f  = tid & (NF - 1);
        const int h  = head_ids[b0 + bi];
        const int r  = rel_ids[b0 + bi];
        reinterpret_cast<float*>(&sA[bi][0])[f] =
            (NL[(size_t)h * NF + f] - c[f]) * sQ[f];
        reinterpret_cast<float*>(&sW[bi][0])[f] = NFW[(size_t)r * NF + f];
    }
    __syncthreads();

    if (e >= E_TOT) return;  // no barriers below

    const float4* nl4 = reinterpret_cast<const float4*>(NL + (size_t)e * NF);
    const float4* q4  = reinterpret_cast<const float4*>(sQ);

    float acc[B_TILE];
#pragma unroll
    for (int bi = 0; bi < B_TILE; ++bi) acc[bi] = 0.0f;

#pragma unroll
    for (int i = 0; i < NF / 4; ++i) {
        const float4 v = nl4[i];   // streamed global load (L3-resident rows)
        const float4 q = q4[i];    // LDS broadcast
        float4 n;
        n.x = v.x * q.x; n.y = v.y * q.y; n.z = v.z * q.z; n.w = v.w * q.w;
#pragma unroll
        for (int bi = 0; bi < B_TILE; ++bi) {
            const float4 a = sA[bi][i];  // ds_read_b128 broadcast
            const float4 w = sW[bi][i];
            float t;
            t = a.x - n.x; acc[bi] = fmaf(__builtin_amdgcn_exp2f(-(t * t)), w.x, acc[bi]);
            t = a.y - n.y; acc[bi] = fmaf(__builtin_amdgcn_exp2f(-(t * t)), w.y, acc[bi]);
            t = a.z - n.z; acc[bi] = fmaf(__builtin_amdgcn_exp2f(-(t * t)), w.z, acc[bi]);
            t = a.w - n.w; acc[bi] = fmaf(__builtin_amdgcn_exp2f(-(t * t)), w.w, acc[bi]);
        }
    }

#pragma unroll
    for (int bi = 0; bi < B_TILE; ++bi) {
        out[(size_t)(b0 + bi) * E_TOT + e] = acc[bi];
    }
}

extern "C" void kernel_launch(void* const* d_in, const int* in_sizes, int n_in,
                              void* d_out, int out_size, void* d_ws, size_t ws_size,
                              hipStream_t stream)
{
    const float* NL       = (const float*)d_in[0];
    const float* c        = (const float*)d_in[1];
    const float* varr     = (const float*)d_in[2];
    const float* NFW      = (const float*)d_in[3];
    const int*   head_ids = (const int*)d_in[4];
    const int*   rel_ids  = (const int*)d_in[5];
    float*       out      = (float*)d_out;

    dim3 grid((E_TOT + BLOCK - 1) / BLOCK, B_TOT / B_TILE);
    kbln_kernel<<<grid, dim3(BLOCK), 0, stream>>>(NL, c, varr, NFW, head_ids, rel_ids, out);
}